// Round 2
// 527.435 us; speedup vs baseline: 1.1354x; 1.1354x over previous
//
#include <hip/hip_runtime.h>

// MoE expert FFN: T=256, E=16, H=2048, I=1024, top_k=4 (int32 device scalar).
// Inputs fp32 (proven: bf16-reinterp gave NaN in R1). Output fp32 (proven:
// R2 wrote valid bf16, harness read fp32 -> exact stub error).
// Compute: bf16 MFMA (threshold is 2% of max|ref| -> bf16 precision OK).
//
// R3: gemm1/gemm2 were latency-bound (all pipes <11%, 1 wave/SIMD).
//   - 512-thread blocks, 8 waves: in-block split-K (wave>>2 picks k-half),
//     LDS floatx4 reduction combines partials. 2x waves/SIMD, half the
//     per-wave k-chain, no extra HBM traffic.
//   - mt (token-tile) count trimmed to ceil(count/16) via switch->template.
// R4 FIX: R3 offset the WEIGHT pointers by kh*(K/2) but not the A-row
//   pointers -> kh=1 waves multiplied mismatched k-ranges (absmax 1.44).
//   A-rows now offset identically.
//
//   convert_x    : x fp32 -> bf16 xb (2 MB read, once)
//   route_kernel : softmax+topk -> per-expert token lists + per-token map
//   gemm1_kernel : h = X_e @ w1[e]^T (w1 fp32 streamed once, converted
//                  in-register), fused silu(gate)*up -> act (bf16 ws)
//   gemm2_kernel : y = act_e @ w2[e]^T (w2 fp32 streamed once) -> y (bf16 ws)
//   gather_kernel: out[t] = sum_k wt[k]*y[e_k][slot_k]  (fp32 out, no atomics)

typedef __attribute__((ext_vector_type(8))) short bf16x8;   // MFMA A/B frag (4 VGPRs)
typedef __attribute__((ext_vector_type(4))) float floatx4;  // MFMA C/D frag

#define T_TOK 256
#define N_EXP 16
#define H_DIM 2048
#define I_DIM 1024
#define MAX_SLOTS 256

__device__ __forceinline__ short f2bf(float f) {           // RNE fp32->bf16
    union { float f; unsigned u; } v; v.f = f;
    unsigned r = (v.u + 0x7FFFu + ((v.u >> 16) & 1u)) >> 16;
    return (short)r;
}
__device__ __forceinline__ float bf2f(short s) {
    union { unsigned u; float f; } v; v.u = ((unsigned)(unsigned short)s) << 16;
    return v.f;
}
__device__ __forceinline__ bf16x8 pack2f4(float4 a, float4 b) {  // 8 fp32 -> bf16x8
    bf16x8 r;
    r[0] = f2bf(a.x); r[1] = f2bf(a.y); r[2] = f2bf(a.z); r[3] = f2bf(a.w);
    r[4] = f2bf(b.x); r[5] = f2bf(b.y); r[6] = f2bf(b.z); r[7] = f2bf(b.w);
    return r;
}
__device__ __forceinline__ bf16x8 pack8(const float* __restrict__ p) {
    return pack2f4(*(const float4*)p, *(const float4*)(p + 4));
}

// ---------------- x fp32 -> bf16 ----------------
__global__ __launch_bounds__(256) void convert_x_kernel(
    const float* __restrict__ xf, short* __restrict__ xb)
{
    const int i = (blockIdx.x * 256 + threadIdx.x) * 8;   // 65536 threads * 8 = 524288
    *(bf16x8*)(xb + i) = pack8(xf + i);
}

// ---------------- routing ----------------
__global__ __launch_bounds__(256) void route_kernel(
    const float* __restrict__ logits,   // [256][16] fp32
    const int* __restrict__ topk_ptr,
    int* __restrict__ counts, int* __restrict__ tokens,
    int* __restrict__ tok_e, int* __restrict__ tok_slot, float* __restrict__ tok_wt)
{
    __shared__ int lds_counts[N_EXP];
    const int t = threadIdx.x;
    if (t < N_EXP) lds_counts[t] = 0;
    __syncthreads();

    int K = topk_ptr[0];
    if (K > 8) K = 8;
    if (K < 1) K = 1;

    float l[N_EXP];
    #pragma unroll
    for (int j = 0; j < N_EXP; ++j) l[j] = logits[t * N_EXP + j];

    float M = l[0];
    #pragma unroll
    for (int j = 1; j < N_EXP; ++j) M = fmaxf(M, l[j]);

    // top-K by logit; strict > keeps lowest index on ties (matches lax.top_k)
    int idx[8]; float lv[8]; unsigned used = 0u;
    for (int k = 0; k < K; ++k) {
        int bi = 0; float bv = -1e30f;
        #pragma unroll
        for (int j = 0; j < N_EXP; ++j)
            if (!((used >> j) & 1u) && l[j] > bv) { bv = l[j]; bi = j; }
        used |= 1u << bi;
        idx[k] = bi; lv[k] = bv;
    }
    // softmax restricted to top-K == renormalized top-K softmax probs
    float w[8], s = 0.f;
    for (int k = 0; k < K; ++k) { w[k] = __expf(lv[k] - M); s += w[k]; }
    const float inv = 1.0f / s;

    for (int k = 0; k < K; ++k) {
        const int e = idx[k];
        const int slot = atomicAdd(&lds_counts[e], 1);
        tokens[e * MAX_SLOTS + slot] = t;
        tok_e[t * 8 + k] = e; tok_slot[t * 8 + k] = slot; tok_wt[t * 8 + k] = w[k] * inv;
    }
    __syncthreads();
    if (t < N_EXP) counts[t] = lds_counts[t];
}

// ---------------- GEMM1: h = X_e @ w1[e]^T, act = silu(gate)*up ----------------
// grid (16 experts, 16 i-blocks of 64). 512 threads = 8 waves:
//   wave&3 = i-wave (16 i each), wave>>2 = k-half (0:[0,1024) 1:[1024,2048)).
// Upper k-half writes partial acc to LDS; lower k-half adds + silu + store.
// NOTE: both the weight row pointers AND the A-row reads are offset by
// kh*(H_DIM/2) — they must cover the SAME k-range (R4 fix).
template<int MT>
__device__ __forceinline__ void g1_ms(
    int ms, int count, const int* __restrict__ toks, const short* __restrict__ xb,
    const float* __restrict__ wg, const float* __restrict__ wu,
    int quad, int nl, int lane, int iw, int kh, int i_base, int e,
    short* __restrict__ act, floatx4* red)
{
    const short* xr[MT];
    #pragma unroll
    for (int mt = 0; mt < MT; ++mt) {
        int s = ms + mt * 16 + nl;
        if (s >= count) s = count - 1;     // clamp: padded rows dropped at store
        xr[mt] = xb + (size_t)toks[s] * H_DIM + kh * (H_DIM / 2);   // R4 fix
    }
    floatx4 ag[MT], au[MT];
    #pragma unroll
    for (int mt = 0; mt < MT; ++mt) { ag[mt] = (floatx4)0.0f; au[mt] = (floatx4)0.0f; }

    for (int k = 0; k < H_DIM / 2; k += 32) {
        const int ko = k + quad * 8;
        // issue all loads first (ILP), then convert, then MFMA
        float4 g0 = *(const float4*)(wg + ko), g1 = *(const float4*)(wg + ko + 4);
        float4 u0 = *(const float4*)(wu + ko), u1 = *(const float4*)(wu + ko + 4);
        bf16x8 av[MT];
        #pragma unroll
        for (int mt = 0; mt < MT; ++mt) av[mt] = *(const bf16x8*)(xr[mt] + ko);
        bf16x8 bg = pack2f4(g0, g1);
        bf16x8 bu = pack2f4(u0, u1);
        #pragma unroll
        for (int mt = 0; mt < MT; ++mt) {
            ag[mt] = __builtin_amdgcn_mfma_f32_16x16x32_bf16(av[mt], bg, ag[mt], 0, 0, 0);
            au[mt] = __builtin_amdgcn_mfma_f32_16x16x32_bf16(av[mt], bu, au[mt], 0, 0, 0);
        }
    }
    // cross-k-half reduction via LDS: [iw][mt][gu][lane] floatx4, 64 KB max
    if (kh) {
        #pragma unroll
        for (int mt = 0; mt < MT; ++mt) {
            red[(((iw * 8 + mt) * 2 + 0) * 64) + lane] = ag[mt];
            red[(((iw * 8 + mt) * 2 + 1) * 64) + lane] = au[mt];
        }
    }
    __syncthreads();
    if (!kh) {
        #pragma unroll
        for (int mt = 0; mt < MT; ++mt) {
            floatx4 g = ag[mt] + red[(((iw * 8 + mt) * 2 + 0) * 64) + lane];
            floatx4 u = au[mt] + red[(((iw * 8 + mt) * 2 + 1) * 64) + lane];
            #pragma unroll
            for (int r = 0; r < 4; ++r) {
                const int slot = ms + mt * 16 + quad * 4 + r;   // D: row=quad*4+r, col=nl
                if (slot < count) {
                    const float gv = g[r], uv = u[r];
                    const float a = gv / (1.0f + __expf(-gv)) * uv;   // silu(g)*u
                    act[(size_t)(e * MAX_SLOTS + slot) * I_DIM + i_base + nl] = f2bf(a);
                }
            }
        }
    }
    __syncthreads();   // protect LDS reuse on next ms iteration
}

__global__ __launch_bounds__(512, 2) void gemm1_kernel(
    const short* __restrict__ xb,     // [256][2048] bf16
    const float* __restrict__ w1,     // [16][2048][2048] fp32
    const int* __restrict__ counts, const int* __restrict__ tokens,
    short* __restrict__ act)          // [16][256][1024] bf16
{
    __shared__ floatx4 red[4 * 8 * 2 * 64];    // 64 KB
    const int e = blockIdx.x;
    const int count = counts[e];
    if (count == 0) return;
    const int tid = (int)threadIdx.x;
    const int wave = tid >> 6, lane = tid & 63;
    const int iw = wave & 3, kh = wave >> 2;
    const int nl = lane & 15, quad = lane >> 4;
    const int i_base = blockIdx.y * 64 + iw * 16;

    const float* wg = w1 + ((size_t)e * H_DIM + (i_base + nl)) * H_DIM + kh * (H_DIM / 2);
    const float* wu = w1 + ((size_t)e * H_DIM + (I_DIM + i_base + nl)) * H_DIM + kh * (H_DIM / 2);
    const int* toks = tokens + e * MAX_SLOTS;

    for (int ms = 0; ms < count; ms += 128) {
        const int rem = count - ms;
        const int nmt = rem >= 128 ? 8 : ((rem + 15) >> 4);   // block-uniform
        switch (nmt) {
            case 1: g1_ms<1>(ms, count, toks, xb, wg, wu, quad, nl, lane, iw, kh, i_base, e, act, red); break;
            case 2: g1_ms<2>(ms, count, toks, xb, wg, wu, quad, nl, lane, iw, kh, i_base, e, act, red); break;
            case 3: g1_ms<3>(ms, count, toks, xb, wg, wu, quad, nl, lane, iw, kh, i_base, e, act, red); break;
            case 4: g1_ms<4>(ms, count, toks, xb, wg, wu, quad, nl, lane, iw, kh, i_base, e, act, red); break;
            case 5: g1_ms<5>(ms, count, toks, xb, wg, wu, quad, nl, lane, iw, kh, i_base, e, act, red); break;
            case 6: g1_ms<6>(ms, count, toks, xb, wg, wu, quad, nl, lane, iw, kh, i_base, e, act, red); break;
            case 7: g1_ms<7>(ms, count, toks, xb, wg, wu, quad, nl, lane, iw, kh, i_base, e, act, red); break;
            default: g1_ms<8>(ms, count, toks, xb, wg, wu, quad, nl, lane, iw, kh, i_base, e, act, red); break;
        }
    }
}

// ---------------- GEMM2: y = act_e @ w2[e]^T ----------------
// grid (16 experts, 32 h-blocks of 64). 512 threads = 8 waves (i-wave x k-half).
template<int MT>
__device__ __forceinline__ void g2_ms(
    int ms, int count, const short* __restrict__ acte,
    const float* __restrict__ wr,
    int quad, int nl, int lane, int iw, int kh, int h_base, int e,
    short* __restrict__ y, floatx4* red)
{
    const short* ar[MT];
    #pragma unroll
    for (int mt = 0; mt < MT; ++mt) {
        int s = ms + mt * 16 + nl;
        if (s >= count) s = count - 1;
        ar[mt] = acte + (size_t)s * I_DIM + kh * (I_DIM / 2);   // R4 fix
    }
    floatx4 acc[MT];
    #pragma unroll
    for (int mt = 0; mt < MT; ++mt) acc[mt] = (floatx4)0.0f;

    for (int k = 0; k < I_DIM / 2; k += 32) {
        const int ko = k + quad * 8;
        float4 b0 = *(const float4*)(wr + ko), b1 = *(const float4*)(wr + ko + 4);
        bf16x8 av[MT];
        #pragma unroll
        for (int mt = 0; mt < MT; ++mt) av[mt] = *(const bf16x8*)(ar[mt] + ko);
        bf16x8 b = pack2f4(b0, b1);
        #pragma unroll
        for (int mt = 0; mt < MT; ++mt)
            acc[mt] = __builtin_amdgcn_mfma_f32_16x16x32_bf16(av[mt], b, acc[mt], 0, 0, 0);
    }
    if (kh) {
        #pragma unroll
        for (int mt = 0; mt < MT; ++mt) red[(iw * 8 + mt) * 64 + lane] = acc[mt];
    }
    __syncthreads();
    if (!kh) {
        #pragma unroll
        for (int mt = 0; mt < MT; ++mt) {
            floatx4 a = acc[mt] + red[(iw * 8 + mt) * 64 + lane];
            #pragma unroll
            for (int r = 0; r < 4; ++r) {
                const int slot = ms + mt * 16 + quad * 4 + r;
                if (slot < count)
                    y[(size_t)(e * MAX_SLOTS + slot) * H_DIM + h_base + nl] = f2bf(a[r]);
            }
        }
    }
    __syncthreads();
}

__global__ __launch_bounds__(512, 4) void gemm2_kernel(
    const short* __restrict__ act,    // [16][256][1024] bf16
    const float* __restrict__ w2,     // [16][2048][1024] fp32
    const int* __restrict__ counts,
    short* __restrict__ y)            // [16][256][2048] bf16
{
    __shared__ floatx4 red[4 * 8 * 64];    // 32 KB (2 blocks/CU -> 64 KB)
    const int e = blockIdx.x;
    const int count = counts[e];
    if (count == 0) return;
    const int tid = (int)threadIdx.x;
    const int wave = tid >> 6, lane = tid & 63;
    const int iw = wave & 3, kh = wave >> 2;
    const int nl = lane & 15, quad = lane >> 4;
    const int h_base = blockIdx.y * 64 + iw * 16;

    const float* wr = w2 + ((size_t)e * H_DIM + h_base + nl) * I_DIM + kh * (I_DIM / 2);
    const short* acte = act + (size_t)e * MAX_SLOTS * I_DIM;

    for (int ms = 0; ms < count; ms += 128) {
        const int rem = count - ms;
        const int nmt = rem >= 128 ? 8 : ((rem + 15) >> 4);
        switch (nmt) {
            case 1: g2_ms<1>(ms, count, acte, wr, quad, nl, lane, iw, kh, h_base, e, y, red); break;
            case 2: g2_ms<2>(ms, count, acte, wr, quad, nl, lane, iw, kh, h_base, e, y, red); break;
            case 3: g2_ms<3>(ms, count, acte, wr, quad, nl, lane, iw, kh, h_base, e, y, red); break;
            case 4: g2_ms<4>(ms, count, acte, wr, quad, nl, lane, iw, kh, h_base, e, y, red); break;
            case 5: g2_ms<5>(ms, count, acte, wr, quad, nl, lane, iw, kh, h_base, e, y, red); break;
            case 6: g2_ms<6>(ms, count, acte, wr, quad, nl, lane, iw, kh, h_base, e, y, red); break;
            case 7: g2_ms<7>(ms, count, acte, wr, quad, nl, lane, iw, kh, h_base, e, y, red); break;
            default: g2_ms<8>(ms, count, acte, wr, quad, nl, lane, iw, kh, h_base, e, y, red); break;
        }
    }
}

// ---------------- gather: out[t][h] = sum_k wt * y[e_k][slot_k][h] (fp32) ----------------
__global__ __launch_bounds__(256) void gather_kernel(
    const short* __restrict__ y, const int* __restrict__ topk_ptr,
    const int* __restrict__ tok_e, const int* __restrict__ tok_slot,
    const float* __restrict__ tok_wt, float* __restrict__ out)
{
    const int t = blockIdx.x;
    int K = topk_ptr[0];
    if (K > 8) K = 8;
    if (K < 1) K = 1;
    int e[8], sl[8]; float w[8];
    for (int k = 0; k < K; ++k) {
        e[k] = tok_e[t * 8 + k]; sl[k] = tok_slot[t * 8 + k]; w[k] = tok_wt[t * 8 + k];
    }
    for (int h = threadIdx.x; h < H_DIM; h += 256) {
        float s = 0.f;
        for (int k = 0; k < K; ++k)
            s += w[k] * bf2f(y[(size_t)(e[k] * MAX_SLOTS + sl[k]) * H_DIM + h]);
        out[(size_t)t * H_DIM + h] = s;
    }
}

// ---------------- launch ----------------
extern "C" void kernel_launch(void* const* d_in, const int* in_sizes, int n_in,
                              void* d_out, int out_size, void* d_ws, size_t ws_size,
                              hipStream_t stream)
{
    const float* x  = (const float*)d_in[0];
    const float* rl = (const float*)d_in[1];
    const float* w1 = (const float*)d_in[2];
    const float* w2 = (const float*)d_in[3];
    const int* topk = (const int*)d_in[4];

    char* ws = (char*)d_ws;
    int*   counts   = (int*)  (ws + 0);          //   64 B
    int*   tokens   = (int*)  (ws + 256);        //  16 KB [16][256]
    int*   tok_e    = (int*)  (ws + 16640);      //   8 KB [256][8]
    int*   tok_slot = (int*)  (ws + 24832);      //   8 KB
    float* tok_wt   = (float*)(ws + 33024);      //   8 KB
    short* xb       = (short*)(ws + 65536);      //   1 MB [256][2048] bf16
    short* act      = (short*)(ws + 1114112);    //   8 MB [16][256][1024] bf16
    short* yb       = (short*)(ws + 9502720);    //  16 MB [16][256][2048] bf16

    convert_x_kernel<<<256, 256, 0, stream>>>(x, xb);
    route_kernel<<<1, 256, 0, stream>>>(rl, topk, counts, tokens, tok_e, tok_slot, tok_wt);
    gemm1_kernel<<<dim3(N_EXP, 16), 512, 0, stream>>>(xb, w1, counts, tokens, act);
    gemm2_kernel<<<dim3(N_EXP, 32), 512, 0, stream>>>(act, w2, counts, yb);
    gather_kernel<<<T_TOK, 256, 0, stream>>>(yb, topk, tok_e, tok_slot, tok_wt, (float*)d_out);
}